// Round 15
// baseline (144.313 us; speedup 1.0000x reference)
//
#include <hip/hip_runtime.h>
#include <cstdint>
#include <cstddef>

#define NTOK 16384
#define FDIM 32
#define HDIM 128
#define TOKB 32

typedef __attribute__((ext_vector_type(8))) short short8;     // bf16x8 MFMA frag
typedef __attribute__((ext_vector_type(4))) float float4v;
typedef __attribute__((ext_vector_type(2))) float float2v;
typedef __attribute__((ext_vector_type(4))) unsigned int uint4v;

__device__ __forceinline__ float elu_f(float x)  { return x > 0.f ? x : __expf(x) - 1.f; }
__device__ __forceinline__ float sigm_f(float x) { return 1.f / (1.f + __expf(-x)); }

// fp32 -> bf16 RNE
__device__ __forceinline__ unsigned int f2bf(float f) {
  unsigned int u = __float_as_uint(f);
  u += 0x7FFFu + ((u >> 16) & 1u);
  return u >> 16;
}
// packed fp32x2 -> bf16x2 in one VALU op (RNE)
__device__ __forceinline__ unsigned int cvtpk(float lo, float hi) {
  unsigned int r;
  asm("v_cvt_pk_bf16_f32 %0, %1, %2" : "=v"(r) : "v"(lo), "v"(hi));
  return r;
}

// ---------------------------------------------------------------------------
// Kernel 1 v15:
//  Blocks [0,128): fcomb = fw2 @ fglu_w (validated R5-R14 form), TILE-MAJOR
//    bfrag + scal pack.
//  Blocks [128, 128+1024): weight-GRN + softmax, 4 TOKENS PER WAVE (weight
//    loads amortized 4x) at high occupancy (~8 blocks/CU, 32 waves/CU — the
//    R13 low-occupancy failure mode avoided; R14's 2-token variant validated
//    the mechanism). 16 tokens/block. Scratch: 4x256 floats per wave (16 KB).
// ---------------------------------------------------------------------------
__global__ __launch_bounds__(256) void k_pw(
    const float* __restrict__ x,
    const float* __restrict__ fw2, const float* __restrict__ fb2,
    const float* __restrict__ fglu_w, const float* __restrict__ fglu_b,
    const float* __restrict__ fskip, const float* __restrict__ flng,
    const float* __restrict__ flnb,
    const float* __restrict__ ww1, const float* __restrict__ wb1,
    const float* __restrict__ ww2, const float* __restrict__ wb2,
    const float* __restrict__ wglu_w, const float* __restrict__ wglu_b,
    const float* __restrict__ wln_g, const float* __restrict__ wln_b,
    unsigned short* __restrict__ bfrag, float* __restrict__ scal,
    float* __restrict__ wout)
{
  __shared__ __align__(16) float smem[4096];
  const int tid = threadIdx.x;

  if (blockIdx.x < 128) {
    // ---------------- fcomb (validated R5-R14 form) ----------------
    const int f  = blockIdx.x >> 2;
    const int ks = blockIdx.x & 3;
    const float* src = fw2 + ((size_t)f * 128 + ks * 32) * 128;
    for (int i = 0; i < 4; ++i) {
      int vi = tid + i * 256;
      *(float4v*)&smem[vi * 4] = *(const float4v*)&src[vi * 4];
    }
    __syncthreads();

    const int o2 = tid;
    float acc[32];
#pragma unroll
    for (int kk = 0; kk < 32; ++kk) acc[kk] = 0.f;
    float bacc = 0.f;

    for (int o = 0; o < 128; o += 4) {
      float gv0 = fglu_w[((size_t)f * 128 + o + 0) * 256 + o2];
      float gv1 = fglu_w[((size_t)f * 128 + o + 1) * 256 + o2];
      float gv2 = fglu_w[((size_t)f * 128 + o + 2) * 256 + o2];
      float gv3 = fglu_w[((size_t)f * 128 + o + 3) * 256 + o2];
      bacc += fb2[f * 128 + o + 0] * gv0 + fb2[f * 128 + o + 1] * gv1
            + fb2[f * 128 + o + 2] * gv2 + fb2[f * 128 + o + 3] * gv3;
#pragma unroll
      for (int kk = 0; kk < 32; ++kk) {
        float4v a4 = *(const float4v*)&smem[kk * 128 + o];
        acc[kk] += a4[0] * gv0 + a4[1] * gv1 + a4[2] * gv2 + a4[3] * gv3;
      }
    }

    const int type = o2 >> 7;
    const int h    = o2 & 127;
    const int w2   = h >> 4;
    const int r    = h & 15;
    const size_t tbase = ((((size_t)f * 8 + w2) * 2 + type) * 4 + ks) * 512;
#pragma unroll
    for (int gg = 0; gg < 4; ++gg) {
      uint4v pk;
      pk[0] = f2bf(acc[gg * 8 + 0]) | (f2bf(acc[gg * 8 + 1]) << 16);
      pk[1] = f2bf(acc[gg * 8 + 2]) | (f2bf(acc[gg * 8 + 3]) << 16);
      pk[2] = f2bf(acc[gg * 8 + 4]) | (f2bf(acc[gg * 8 + 5]) << 16);
      pk[3] = f2bf(acc[gg * 8 + 6]) | (f2bf(acc[gg * 8 + 7]) << 16);
      *(uint4v*)(bfrag + tbase + (size_t)(r + gg * 16) * 8) = pk;
    }
    if (ks == 0) {
      scal[f * 640 + type * 128 + h] = bacc + fglu_b[f * 256 + o2];
      if (type == 0) {
        scal[f * 640 + 256 + h] = fskip[f * 128 + h];
        scal[f * 640 + 384 + h] = flng[f * 128 + h];
        scal[f * 640 + 512 + h] = flnb[f * 128 + h];
      }
    }

  } else {
    // ------- weight-GRN + softmax: 4 tokens per wave (4-chain ILP) -------
    const int bid = blockIdx.x - 128;
    const int wv  = tid >> 6;
    const int l   = tid & 63;
    const int o   = l & 31;
    const int half = l >> 5;
    const int tb  = bid * 16 + wv * 4;   // first token of this wave
    // per-token slice: [0..32) x, [32..160) wh, [160..192) wh2; stride 256
    float* S = smem + wv * 1024;

    float xv[4];
#pragma unroll
    for (int g = 0; g < 4; ++g) {
      xv[g] = x[(size_t)(tb + g) * 32 + o];
      if (l < 32) S[g * 256 + l] = xv[g];
    }
    float a0[4], a1[4];
#pragma unroll
    for (int g = 0; g < 4; ++g) { a0[g] = wb1[l]; a1[g] = wb1[l + 64]; }
    __syncthreads();

    for (int f2 = 0; f2 < 32; ++f2) {
      float w1a = ww1[f2 * 128 + l];
      float w1b = ww1[f2 * 128 + l + 64];
#pragma unroll
      for (int g = 0; g < 4; ++g) {
        float xf = S[g * 256 + f2];
        a0[g] = fmaf(xf, w1a, a0[g]);
        a1[g] = fmaf(xf, w1b, a1[g]);
      }
    }
#pragma unroll
    for (int g = 0; g < 4; ++g) {
      S[g * 256 + 32 + l]      = elu_f(a0[g]);
      S[g * 256 + 32 + l + 64] = elu_f(a1[g]);
    }
    __syncthreads();

    float b[4] = {0.f, 0.f, 0.f, 0.f};
    for (int hh = 0; hh < 64; ++hh) {
      float w2v = ww2[(half * 64 + hh) * 32 + o];
#pragma unroll
      for (int g = 0; g < 4; ++g)
        b[g] = fmaf(S[g * 256 + 32 + half * 64 + hh], w2v, b[g]);
    }
#pragma unroll
    for (int g = 0; g < 4; ++g) {
      b[g] += __shfl_xor(b[g], 32);
      b[g] += wb2[o];
      if (l < 32) S[g * 256 + 160 + l] = b[g];
    }
    __syncthreads();

    float gg4[4];
#pragma unroll
    for (int g = 0; g < 4; ++g) gg4[g] = wglu_b[l];
    for (int oi = 0; oi < 32; ++oi) {
      float wv2 = wglu_w[oi * 64 + l];
#pragma unroll
      for (int g = 0; g < 4; ++g)
        gg4[g] = fmaf(S[g * 256 + 160 + oi], wv2, gg4[g]);
    }

    // GLU + skip + LN + softmax per token
#pragma unroll
    for (int g = 0; g < 4; ++g) {
      float gate = __shfl_xor(gg4[g], 32);
      float y = gg4[g] * sigm_f(gate) + xv[g];
      float s = y;
      s += __shfl_xor(s, 1); s += __shfl_xor(s, 2); s += __shfl_xor(s, 4);
      s += __shfl_xor(s, 8); s += __shfl_xor(s, 16);
      float mean = s * (1.f / 32.f);
      float d = y - mean;
      float ss = d * d;
      ss += __shfl_xor(ss, 1); ss += __shfl_xor(ss, 2); ss += __shfl_xor(ss, 4);
      ss += __shfl_xor(ss, 8); ss += __shfl_xor(ss, 16);
      float rstd = rsqrtf(ss * (1.f / 32.f) + 1e-5f);
      float ln = d * rstd * wln_g[o] + wln_b[o];
      float mx = ln;
      mx = fmaxf(mx, __shfl_xor(mx, 1));  mx = fmaxf(mx, __shfl_xor(mx, 2));
      mx = fmaxf(mx, __shfl_xor(mx, 4));  mx = fmaxf(mx, __shfl_xor(mx, 8));
      mx = fmaxf(mx, __shfl_xor(mx, 16));
      float e = __expf(ln - mx);
      float se = e;
      se += __shfl_xor(se, 1); se += __shfl_xor(se, 2); se += __shfl_xor(se, 4);
      se += __shfl_xor(se, 8); se += __shfl_xor(se, 16);
      if (l < 32) wout[(size_t)(tb + g) * 32 + l] = e / se;
    }
  }
}

// ---------------------------------------------------------------------------
// Kernel 2: EXACT R9 champion (126us, bit-stable across R13/R14): 2 features
// per barrier, 4-buf a_lds, deferred finalize, LDS atomicAdd + 3-buffer sred,
// 36 carried regs.
// ---------------------------------------------------------------------------
__global__ __launch_bounds__(512, 4) void k_main(
    const float* __restrict__ x,
    const float* __restrict__ fw1, const float* __restrict__ fb1,
    const unsigned short* __restrict__ bfrag, const float* __restrict__ scal,
    const float* __restrict__ wts, float* __restrict__ out)
{
  __shared__ __align__(16) unsigned short a_lds[4][TOKB * 128]; // 4 x 8 KB
  __shared__ __align__(16) float x_lds[FDIM * TOKB];            // [f][t] 4 KB
  __shared__ __align__(16) float w_lds[FDIM * TOKB];            // [f][t] 4 KB
  __shared__ __align__(16) float sred[3][2][2][TOKB];           // 1.5 KB

  const int tid = threadIdx.x;
  const int w   = tid >> 6;
  const int l   = tid & 63;
  const int tk  = l & 15;        // token within a 16-token tile
  const int rg  = l >> 4;        // row-group: lane's 4 h's = h0..h0+3
  const int t0  = blockIdx.x * TOKB;
  const int h0  = w * 16 + rg * 4;
  const int st  = tid >> 4;            // staging token 0..31
  const int sk  = (tid & 15) * 8;      // staging k 0..120
  const int stg_byte = (st * 256 + sk * 2) ^ ((st & 7) << 4);

  // prologue: stage x,w transposed to [f][t]; zero all sred buffers
  {
    float2v xv = *(const float2v*)(x   + (size_t)t0 * FDIM + tid * 2);
    float2v wv = *(const float2v*)(wts + (size_t)t0 * FDIM + tid * 2);
#pragma unroll
    for (int e = 0; e < 2; ++e) {
      int flat = tid * 2 + e;
      int tt = flat >> 5, ff = flat & 31;
      x_lds[ff * TOKB + tt] = xv[e];
      w_lds[ff * TOKB + tt] = wv[e];
    }
    if (tid < 384) ((float*)sred)[tid] = 0.f;
  }

  float4v oa0 = (float4v){0.f, 0.f, 0.f, 0.f};
  float4v oa1 = (float4v){0.f, 0.f, 0.f, 0.f};
  // carried prev-pair state (feature A = even, B = odd of the previous pair)
  float4v pyA0 = oa0, pyA1 = oa0, pyB0 = oa0, pyB1 = oa0;
  float4v plgA = oa0, plbA = oa0, plgB = oa0, plbB = oa0;
  float pwtA0 = 0.f, pwtA1 = 0.f, pwtB0 = 0.f, pwtB1 = 0.f;

  __syncthreads();   // x_lds/w_lds/sred ready

  int p = 0;   // pair-buffer index = k % 3
#pragma unroll 1
  for (int k = 0; k < FDIM / 2; ++k) {
    const int g    = 2 * k;
    const int bufp = (k & 1) * 2;

    // ---- A-frags for feature g (issued early; consumed after barrier) ----
    short8 aV[4], aG[4];
    {
      const unsigned short* bb = bfrag + (((size_t)g * 8 + w) * 8) * 512 + (size_t)l * 8;
#pragma unroll
      for (int ks = 0; ks < 4; ++ks) {
        aV[ks] = *(const short8*)(bb + (size_t)ks * 512);
        aG[ks] = *(const short8*)(bb + (size_t)(4 + ks) * 512);
      }
    }

    // ---- stage h1(g) -> a_lds[bufp] ----
    {
      float xf = x_lds[g * TOKB + st];
      float4v w1a = *(const float4v*)(fw1 + g * HDIM + sk);
      float4v w1b = *(const float4v*)(fw1 + g * HDIM + sk + 4);
      float4v b1a = *(const float4v*)(fb1 + g * HDIM + sk);
      float4v b1b = *(const float4v*)(fb1 + g * HDIM + sk + 4);
      uint4v pk;
      pk[0] = cvtpk(elu_f(fmaf(xf, w1a[0], b1a[0])),
                    elu_f(fmaf(xf, w1a[1], b1a[1])));
      pk[1] = cvtpk(elu_f(fmaf(xf, w1a[2], b1a[2])),
                    elu_f(fmaf(xf, w1a[3], b1a[3])));
      pk[2] = cvtpk(elu_f(fmaf(xf, w1b[0], b1b[0])),
                    elu_f(fmaf(xf, w1b[1], b1b[1])));
      pk[3] = cvtpk(elu_f(fmaf(xf, w1b[2], b1b[2])),
                    elu_f(fmaf(xf, w1b[3], b1b[3])));
      *(uint4v*)((char*)a_lds[bufp] + stg_byte) = pk;
    }
    // ---- stage h1(g+1) -> a_lds[bufp+1] ----
    {
      float xf = x_lds[(g + 1) * TOKB + st];
      float4v w1a = *(const float4v*)(fw1 + (g + 1) * HDIM + sk);
      float4v w1b = *(const float4v*)(fw1 + (g + 1) * HDIM + sk + 4);
      float4v b1a = *(const float4v*)(fb1 + (g + 1) * HDIM + sk);
      float4v b1b = *(const float4v*)(fb1 + (g + 1) * HDIM + sk + 4);
      uint4v pk;
      pk[0] = cvtpk(elu_f(fmaf(xf, w1a[0], b1a[0])),
                    elu_f(fmaf(xf, w1a[1], b1a[1])));
      pk[1] = cvtpk(elu_f(fmaf(xf, w1a[2], b1a[2])),
                    elu_f(fmaf(xf, w1a[3], b1a[3])));
      pk[2] = cvtpk(elu_f(fmaf(xf, w1b[0], b1b[0])),
                    elu_f(fmaf(xf, w1b[1], b1b[1])));
      pk[3] = cvtpk(elu_f(fmaf(xf, w1b[2], b1b[2])),
                    elu_f(fmaf(xf, w1b[3], b1b[3])));
      *(uint4v*)((char*)a_lds[bufp + 1] + stg_byte) = pk;
    }

    __syncthreads();   // B_k: buffers ready; atomics of pair k-1 visible

    // ---- deferred LN finalize for pair k-1 ----
    if (k > 0) {
      const int pp = (p == 0) ? 2 : p - 1;
      {   // feature A = 2(k-1)
        float sA  = sred[pp][0][0][tk],      ssA = sred[pp][0][1][tk];
        float sB  = sred[pp][0][0][16 + tk], ssB = sred[pp][0][1][16 + tk];
        float m0 = sA * (1.f / 128.f);
        float m1 = sB * (1.f / 128.f);
        float v0 = fmaf(-m0, m0, ssA * (1.f / 128.f));
        float v1 = fmaf(-m1, m1, ssB * (1.f / 128.f));
        float rw0 = rsqrtf(v0 + 1e-5f) * pwtA0;
        float rw1 = rsqrtf(v1 + 1e-5f) * pwtA1;
#pragma unroll
        for (int i = 0; i < 4; ++i) {
          oa0[i] = fmaf((pyA0[i] - m0) * rw0, plgA[i], fmaf(pwtA0, plbA[i], oa0[i]));
          oa1[i] = fmaf((pyA1[i] - m1) * rw1, plgA[i], fmaf(pwtA1, plbA[i], oa1[i]));
        }
      }
      {   // feature B = 2(k-1)+1
        float sA  = sred[pp][1][0][tk],      ssA = sred[pp][1][1][tk];
        float sB  = sred[pp][1][0][16 + tk], ssB = sred[pp][1][1][16 + tk];
        float m0 = sA * (1.f / 128.f);
        float m1 = sB * (1.f / 128.f);
        float v0 = fmaf(-m0, m0, ssA * (1.f / 128.f));
        float v1 = fmaf(-m1, m1, ssB * (1.f / 128.f));
        float rw0 = rsqrtf(v0 + 1e-5f) * pwtB0;
        float rw1 = rsqrtf(v1 + 1e-5f) * pwtB1;
#pragma unroll
        for (int i = 0; i < 4; ++i) {
          oa0[i] = fmaf((pyB0[i] - m0) * rw0, plgB[i], fmaf(pwtB0, plbB[i], oa0[i]));
          oa1[i] = fmaf((pyB1[i] - m1) * rw1, plgB[i], fmaf(pwtB1, plbB[i], oa1[i]));
        }
      }
    }

    // ================= feature g =================
    {
      const float* sp = scal + (size_t)g * 640 + h0;
      float4v bcv = *(const float4v*)(sp);
      float4v bcg = *(const float4v*)(sp + 128);
      float4v fs4 = *(const float4v*)(sp + 256);
      float4v lg4 = *(const float4v*)(sp + 384);
      float4v lb4 = *(const float4v*)(sp + 512);

      float4v av0 = (float4v){0.f,0.f,0.f,0.f}, ag0 = av0, av1 = av0, ag1 = av0;
#pragma unroll
      for (int ks = 0; ks < 4; ++ks) {
        int b0 = tk * 256 + (ks * 32 + rg * 8) * 2;
        b0 ^= (tk & 7) << 4;
        short8 hf0 = *(const short8*)((const char*)a_lds[bufp] + b0);
        int b1 = (16 + tk) * 256 + (ks * 32 + rg * 8) * 2;
        b1 ^= (tk & 7) << 4;
        short8 hf1 = *(const short8*)((const char*)a_lds[bufp] + b1);
        av0 = __builtin_amdgcn_mfma_f32_16x16x32_bf16(aV[ks], hf0, av0, 0, 0, 0);
        ag0 = __builtin_amdgcn_mfma_f32_16x16x32_bf16(aG[ks], hf0, ag0, 0, 0, 0);
        av1 = __builtin_amdgcn_mfma_f32_16x16x32_bf16(aV[ks], hf1, av1, 0, 0, 0);
        ag1 = __builtin_amdgcn_mfma_f32_16x16x32_bf16(aG[ks], hf1, ag1, 0, 0, 0);
      }

      float xt0 = x_lds[g * TOKB + tk],      wt0 = w_lds[g * TOKB + tk];
      float xt1 = x_lds[g * TOKB + 16 + tk], wt1 = w_lds[g * TOKB + 16 + tk];
      float s0 = 0.f, ss0 = 0.f, s1 = 0.f, ss1 = 0.f;
#pragma unroll
      for (int i = 0; i < 4; ++i) {
        float ya = fmaf(xt0, fs4[i], (av0[i] + bcv[i]) * sigm_f(ag0[i] + bcg[i]));
        float yb = fmaf(xt1, fs4[i], (av1[i] + bcv[i]) * sigm_f(ag1[i] + bcg[i]));
        pyA0[i] = ya; pyA1[i] = yb;
        s0 += ya; ss0 = fmaf(ya, ya, ss0);
        s1 += yb; ss1 = fmaf(yb, yb, ss1);
      }
      s0  += __shfl_xor(s0, 16);  s0  += __shfl_xor(s0, 32);
      ss0 += __shfl_xor(ss0, 16); ss0 += __shfl_xor(ss0, 32);
      s1  += __shfl_xor(s1, 16);  s1  += __shfl_xor(s1, 32);
      ss1 += __shfl_xor(ss1, 16); ss1 += __shfl_xor(ss1, 32);
      if (rg == 0) {
        atomicAdd(&sred[p][0][0][tk], s0);
        atomicAdd(&sred[p][0][0][16 + tk], s1);
      } else if (rg == 1) {
        atomicAdd(&sred[p][0][1][tk], ss0);
        atomicAdd(&sred[p][0][1][16 + tk], ss1);
      }
      plgA = lg4; plbA = lb4; pwtA0 = wt0; pwtA1 = wt1;
    }

    // ---- A-frags for feature g+1 (reuse aV/aG registers) ----
    {
      const unsigned short* bb = bfrag + (((size_t)(g + 1) * 8 + w) * 8) * 512 + (size_t)l * 8;
#pragma unroll
      for (int ks = 0; ks < 4; ++ks) {
        aV[ks] = *(const short8*)(bb + (size_t)ks * 512);
        aG[ks] = *(const short8*)(bb + (size_t)(4 + ks) * 512);
      }
    }

    // ================= feature g+1 =================
    {
      const float* sp = scal + (size_t)(g + 1) * 640 + h0;
      float4v bcv = *(const float4v*)(sp);
      float4v bcg = *(const float4v*)(sp + 128);
      float4v fs4 = *(const float4v*)(sp + 256);
      float4v lg4 = *(const float4v*)(sp + 384);
      float4v lb4 = *(const float4v*)(sp + 512);

      float4v av0 = (float4v){0.f,0.f,0.f,0.f}, ag0 = av0, av1 = av0, ag1 = av0;
#pragma unroll
      for (int ks = 0; ks < 4; ++ks) {
        int b0 = tk * 256 + (ks * 32 + rg * 8) * 2;
        b0 ^= (tk & 7) << 4;
        short8 hf0 = *(const short8*)((const char*)a_lds[bufp + 1] + b0);
        int b1 = (16 + tk) * 256 + (ks * 32 + rg * 8) * 2;
        b1 ^= (tk & 7) << 4;
        short8 hf1 = *(const short8*)((const char*)a_lds[bufp + 1] + b1);
        av0 = __builtin_amdgcn_mfma_f32_16x16x32_bf16(aV[ks], hf0, av0, 0, 0, 0);
        ag0 = __builtin_amdgcn_mfma_f32_16x16x32_bf16(aG[ks], hf0, ag0, 0, 0, 0);
        av1 = __builtin_amdgcn_mfma_f32_16x16x32_bf16(aV[ks], hf1, av1, 0, 0, 0);
        ag1 = __builtin_amdgcn_mfma_f32_16x16x32_bf16(aG[ks], hf1, ag1, 0, 0, 0);
      }

      float xt0 = x_lds[(g + 1) * TOKB + tk],      wt0 = w_lds[(g + 1) * TOKB + tk];
      float xt1 = x_lds[(g + 1) * TOKB + 16 + tk], wt1 = w_lds[(g + 1) * TOKB + 16 + tk];
      float s0 = 0.f, ss0 = 0.f, s1 = 0.f, ss1 = 0.f;
#pragma unroll
      for (int i = 0; i < 4; ++i) {
        float ya = fmaf(xt0, fs4[i], (av0[i] + bcv[i]) * sigm_f(ag0[i] + bcg[i]));
        float yb = fmaf(xt1, fs4[i], (av1[i] + bcv[i]) * sigm_f(ag1[i] + bcg[i]));
        pyB0[i] = ya; pyB1[i] = yb;
        s0 += ya; ss0 = fmaf(ya, ya, ss0);
        s1 += yb; ss1 = fmaf(yb, yb, ss1);
      }
      s0  += __shfl_xor(s0, 16);  s0  += __shfl_xor(s0, 32);
      ss0 += __shfl_xor(ss0, 16); ss0 += __shfl_xor(ss0, 32);
      s1  += __shfl_xor(s1, 16);  s1  += __shfl_xor(s1, 32);
      ss1 += __shfl_xor(ss1, 16); ss1 += __shfl_xor(ss1, 32);
      if (rg == 0) {
        atomicAdd(&sred[p][1][0][tk], s0);
        atomicAdd(&sred[p][1][0][16 + tk], s1);
      } else if (rg == 1) {
        atomicAdd(&sred[p][1][1][tk], ss0);
        atomicAdd(&sred[p][1][1][16 + tk], ss1);
      }
      plgB = lg4; plbB = lb4; pwtB0 = wt0; pwtB1 = wt1;
    }

    // zero the pair-buffer used at iter k+1 (barrier-separated both ways)
    {
      const int pn = (p == 2) ? 0 : p + 1;
      if (tid < 128) ((float*)(sred[pn]))[tid] = 0.f;
      p = pn;
    }
  }

  // ---- tail: finalize pair 15 (features 30, 31) ----
  __syncthreads();
  {
    const int pp = (p == 0) ? 2 : p - 1;
    {
      float sA  = sred[pp][0][0][tk],      ssA = sred[pp][0][1][tk];
      float sB  = sred[pp][0][0][16 + tk], ssB = sred[pp][0][1][16 + tk];
      float m0 = sA * (1.f / 128.f);
      float m1 = sB * (1.f / 128.f);
      float v0 = fmaf(-m0, m0, ssA * (1.f / 128.f));
      float v1 = fmaf(-m1, m1, ssB * (1.f / 128.f));
      float rw0 = rsqrtf(v0 + 1e-5f) * pwtA0;
      float rw1 = rsqrtf(v1 + 1e-5f) * pwtA1;
#pragma unroll
      for (int i = 0; i < 4; ++i) {
        oa0[i] = fmaf((pyA0[i] - m0) * rw0, plgA[i], fmaf(pwtA0, plbA[i], oa0[i]));
        oa1[i] = fmaf((pyA1[i] - m1) * rw1, plgA[i], fmaf(pwtA1, plbA[i], oa1[i]));
      }
    }
    {
      float sA  = sred[pp][1][0][tk],      ssA = sred[pp][1][1][tk];
      float sB  = sred[pp][1][0][16 + tk], ssB = sred[pp][1][1][16 + tk];
      float m0 = sA * (1.f / 128.f);
      float m1 = sB * (1.f / 128.f);
      float v0 = fmaf(-m0, m0, ssA * (1.f / 128.f));
      float v1 = fmaf(-m1, m1, ssB * (1.f / 128.f));
      float rw0 = rsqrtf(v0 + 1e-5f) * pwtB0;
      float rw1 = rsqrtf(v1 + 1e-5f) * pwtB1;
#pragma unroll
      for (int i = 0; i < 4; ++i) {
        oa0[i] = fmaf((pyB0[i] - m0) * rw0, plgB[i], fmaf(pwtB0, plbB[i], oa0[i]));
        oa1[i] = fmaf((pyB1[i] - m1) * rw1, plgB[i], fmaf(pwtB1, plbB[i], oa1[i]));
      }
    }
  }

  // ---- store: per lane 2 x 16B contiguous ----
  *(float4v*)(out + (size_t)(t0 + tk) * HDIM + h0)      = oa0;
  *(float4v*)(out + (size_t)(t0 + 16 + tk) * HDIM + h0) = oa1;
}

extern "C" void kernel_launch(void* const* d_in, const int* in_sizes, int n_in,
                              void* d_out, int out_size, void* d_ws, size_t ws_size,
                              hipStream_t stream) {
  const float* x      = (const float*)d_in[0];
  const float* fw1    = (const float*)d_in[1];
  const float* fb1    = (const float*)d_in[2];
  const float* fw2    = (const float*)d_in[3];
  const float* fb2    = (const float*)d_in[4];
  const float* fglu_w = (const float*)d_in[5];
  const float* fglu_b = (const float*)d_in[6];
  const float* fskip  = (const float*)d_in[7];
  const float* fln_g  = (const float*)d_in[8];
  const float* fln_b  = (const float*)d_in[9];
  const float* ww1    = (const float*)d_in[10];
  const float* wb1    = (const float*)d_in[11];
  const float* ww2    = (const float*)d_in[12];
  const float* wb2    = (const float*)d_in[13];
  const float* wglu_w = (const float*)d_in[14];
  const float* wglu_b = (const float*)d_in[15];
  const float* wln_g  = (const float*)d_in[16];
  const float* wln_b  = (const float*)d_in[17];

  float* outp = (float*)d_out;
  float* wout = outp + (size_t)NTOK * HDIM;

  unsigned short* bfrag = (unsigned short*)d_ws;                  // 2 MiB bf16
  float* scal = (float*)((char*)d_ws + (size_t)2 * 1024 * 1024);  // 80 KiB f32

  k_pw<<<dim3(128 + NTOK / 16), dim3(256), 0, stream>>>(
      x, fw2, fb2, fglu_w, fglu_b, fskip, fln_g, fln_b,
      ww1, wb1, ww2, wb2, wglu_w, wglu_b, wln_g, wln_b,
      bfrag, scal, wout);
  k_main<<<dim3(NTOK / TOKB), dim3(512), 0, stream>>>(
      x, fw1, fb1, bfrag, scal, wout, outp);
}

// Round 16
// 138.378 us; speedup vs baseline: 1.0429x; 1.0429x over previous
//
#include <hip/hip_runtime.h>
#include <cstdint>
#include <cstddef>

#define NTOK 16384
#define FDIM 32
#define HDIM 128
#define TOKB 32

typedef __attribute__((ext_vector_type(8))) short short8;     // bf16x8 MFMA frag
typedef __attribute__((ext_vector_type(4))) float float4v;
typedef __attribute__((ext_vector_type(2))) float float2v;
typedef __attribute__((ext_vector_type(4))) unsigned int uint4v;

__device__ __forceinline__ float elu_f(float x)  { return x > 0.f ? x : __expf(x) - 1.f; }
__device__ __forceinline__ float sigm_f(float x) { return 1.f / (1.f + __expf(-x)); }

// fp32 -> bf16 RNE
__device__ __forceinline__ unsigned int f2bf(float f) {
  unsigned int u = __float_as_uint(f);
  u += 0x7FFFu + ((u >> 16) & 1u);
  return u >> 16;
}
// packed fp32x2 -> bf16x2 in one VALU op (RNE)
__device__ __forceinline__ unsigned int cvtpk(float lo, float hi) {
  unsigned int r;
  asm("v_cvt_pk_bf16_f32 %0, %1, %2" : "=v"(r) : "v"(lo), "v"(hi));
  return r;
}

// ---------------------------------------------------------------------------
// Kernel 1 (R14 champion config):
//  Blocks [0,128): fcomb = fw2 @ fglu_w (validated R5-R14 form), TILE-MAJOR
//    bfrag + scal pack.
//  Blocks [128, 128+2048): weight-GRN + softmax, 2 tokens per wave — the
//    measured optimum of the ILP/occupancy trade (1-tok R9 > this by 1us;
//    4-tok R15 and LDS-staged R13 both regressed).
// ---------------------------------------------------------------------------
__global__ __launch_bounds__(256) void k_pw(
    const float* __restrict__ x,
    const float* __restrict__ fw2, const float* __restrict__ fb2,
    const float* __restrict__ fglu_w, const float* __restrict__ fglu_b,
    const float* __restrict__ fskip, const float* __restrict__ flng,
    const float* __restrict__ flnb,
    const float* __restrict__ ww1, const float* __restrict__ wb1,
    const float* __restrict__ ww2, const float* __restrict__ wb2,
    const float* __restrict__ wglu_w, const float* __restrict__ wglu_b,
    const float* __restrict__ wln_g, const float* __restrict__ wln_b,
    unsigned short* __restrict__ bfrag, float* __restrict__ scal,
    float* __restrict__ wout)
{
  __shared__ __align__(16) float smem[4096];
  const int tid = threadIdx.x;

  if (blockIdx.x < 128) {
    // ---------------- fcomb (validated R5-R14 form) ----------------
    const int f  = blockIdx.x >> 2;
    const int ks = blockIdx.x & 3;
    const float* src = fw2 + ((size_t)f * 128 + ks * 32) * 128;
    for (int i = 0; i < 4; ++i) {
      int vi = tid + i * 256;
      *(float4v*)&smem[vi * 4] = *(const float4v*)&src[vi * 4];
    }
    __syncthreads();

    const int o2 = tid;
    float acc[32];
#pragma unroll
    for (int kk = 0; kk < 32; ++kk) acc[kk] = 0.f;
    float bacc = 0.f;

    for (int o = 0; o < 128; o += 4) {
      float gv0 = fglu_w[((size_t)f * 128 + o + 0) * 256 + o2];
      float gv1 = fglu_w[((size_t)f * 128 + o + 1) * 256 + o2];
      float gv2 = fglu_w[((size_t)f * 128 + o + 2) * 256 + o2];
      float gv3 = fglu_w[((size_t)f * 128 + o + 3) * 256 + o2];
      bacc += fb2[f * 128 + o + 0] * gv0 + fb2[f * 128 + o + 1] * gv1
            + fb2[f * 128 + o + 2] * gv2 + fb2[f * 128 + o + 3] * gv3;
#pragma unroll
      for (int kk = 0; kk < 32; ++kk) {
        float4v a4 = *(const float4v*)&smem[kk * 128 + o];
        acc[kk] += a4[0] * gv0 + a4[1] * gv1 + a4[2] * gv2 + a4[3] * gv3;
      }
    }

    const int type = o2 >> 7;
    const int h    = o2 & 127;
    const int w2   = h >> 4;
    const int r    = h & 15;
    const size_t tbase = ((((size_t)f * 8 + w2) * 2 + type) * 4 + ks) * 512;
#pragma unroll
    for (int gg = 0; gg < 4; ++gg) {
      uint4v pk;
      pk[0] = f2bf(acc[gg * 8 + 0]) | (f2bf(acc[gg * 8 + 1]) << 16);
      pk[1] = f2bf(acc[gg * 8 + 2]) | (f2bf(acc[gg * 8 + 3]) << 16);
      pk[2] = f2bf(acc[gg * 8 + 4]) | (f2bf(acc[gg * 8 + 5]) << 16);
      pk[3] = f2bf(acc[gg * 8 + 6]) | (f2bf(acc[gg * 8 + 7]) << 16);
      *(uint4v*)(bfrag + tbase + (size_t)(r + gg * 16) * 8) = pk;
    }
    if (ks == 0) {
      scal[f * 640 + type * 128 + h] = bacc + fglu_b[f * 256 + o2];
      if (type == 0) {
        scal[f * 640 + 256 + h] = fskip[f * 128 + h];
        scal[f * 640 + 384 + h] = flng[f * 128 + h];
        scal[f * 640 + 512 + h] = flnb[f * 128 + h];
      }
    }

  } else {
    // ------- weight-GRN + softmax: 2 tokens per wave (2-chain ILP) -------
    const int bid = blockIdx.x - 128;
    const int wv  = tid >> 6;
    const int l   = tid & 63;
    const int tA  = bid * 8 + wv * 2;
    const int tB  = tA + 1;
    float* S = smem + wv * 512;   // [0..192) token A, [256..448) token B

    float xvA = x[(size_t)tA * 32 + (l & 31)];
    float xvB = x[(size_t)tB * 32 + (l & 31)];
    if (l < 32) { S[l] = xvA; S[256 + l] = xvB; }
    float a0A = wb1[l], a1A = wb1[l + 64];
    float a0B = a0A,    a1B = a1A;
    __syncthreads();
    for (int f2 = 0; f2 < 32; ++f2) {
      float w1a = ww1[f2 * 128 + l];
      float w1b = ww1[f2 * 128 + l + 64];
      float xfA = S[f2], xfB = S[256 + f2];
      a0A = fmaf(xfA, w1a, a0A);  a1A = fmaf(xfA, w1b, a1A);
      a0B = fmaf(xfB, w1a, a0B);  a1B = fmaf(xfB, w1b, a1B);
    }
    a0A = elu_f(a0A); a1A = elu_f(a1A);
    a0B = elu_f(a0B); a1B = elu_f(a1B);
    S[32 + l] = a0A;       S[32 + l + 64] = a1A;
    S[256 + 32 + l] = a0B; S[256 + 32 + l + 64] = a1B;
    __syncthreads();

    const int o    = l & 31;
    const int half = l >> 5;
    float bA = 0.f, bB = 0.f;
    for (int hh = 0; hh < 64; ++hh) {
      float w2v = ww2[(half * 64 + hh) * 32 + o];
      bA = fmaf(S[32 + half * 64 + hh], w2v, bA);
      bB = fmaf(S[256 + 32 + half * 64 + hh], w2v, bB);
    }
    bA += __shfl_xor(bA, 32);  bA += wb2[o];
    bB += __shfl_xor(bB, 32);  bB += wb2[o];
    S[160 + o] = bA;
    S[256 + 160 + o] = bB;
    __syncthreads();

    float gA = wglu_b[l], gB = wglu_b[l];
    for (int o2i = 0; o2i < 32; ++o2i) {
      float wv2 = wglu_w[o2i * 64 + l];
      gA = fmaf(S[160 + o2i], wv2, gA);
      gB = fmaf(S[256 + 160 + o2i], wv2, gB);
    }

    // GLU + skip + LN + softmax (token A then token B)
    {
      float gate = __shfl_xor(gA, 32);
      float y = gA * sigm_f(gate) + xvA;
      float s = y;
      s += __shfl_xor(s, 1); s += __shfl_xor(s, 2); s += __shfl_xor(s, 4);
      s += __shfl_xor(s, 8); s += __shfl_xor(s, 16);
      float mean = s * (1.f / 32.f);
      float d = y - mean;
      float ss = d * d;
      ss += __shfl_xor(ss, 1); ss += __shfl_xor(ss, 2); ss += __shfl_xor(ss, 4);
      ss += __shfl_xor(ss, 8); ss += __shfl_xor(ss, 16);
      float rstd = rsqrtf(ss * (1.f / 32.f) + 1e-5f);
      float ln = d * rstd * wln_g[o] + wln_b[o];
      float mx = ln;
      mx = fmaxf(mx, __shfl_xor(mx, 1));  mx = fmaxf(mx, __shfl_xor(mx, 2));
      mx = fmaxf(mx, __shfl_xor(mx, 4));  mx = fmaxf(mx, __shfl_xor(mx, 8));
      mx = fmaxf(mx, __shfl_xor(mx, 16));
      float e = __expf(ln - mx);
      float se = e;
      se += __shfl_xor(se, 1); se += __shfl_xor(se, 2); se += __shfl_xor(se, 4);
      se += __shfl_xor(se, 8); se += __shfl_xor(se, 16);
      if (l < 32) wout[(size_t)tA * 32 + l] = e / se;
    }
    {
      float gate = __shfl_xor(gB, 32);
      float y = gB * sigm_f(gate) + xvB;
      float s = y;
      s += __shfl_xor(s, 1); s += __shfl_xor(s, 2); s += __shfl_xor(s, 4);
      s += __shfl_xor(s, 8); s += __shfl_xor(s, 16);
      float mean = s * (1.f / 32.f);
      float d = y - mean;
      float ss = d * d;
      ss += __shfl_xor(ss, 1); ss += __shfl_xor(ss, 2); ss += __shfl_xor(ss, 4);
      ss += __shfl_xor(ss, 8); ss += __shfl_xor(ss, 16);
      float rstd = rsqrtf(ss * (1.f / 32.f) + 1e-5f);
      float ln = d * rstd * wln_g[o] + wln_b[o];
      float mx = ln;
      mx = fmaxf(mx, __shfl_xor(mx, 1));  mx = fmaxf(mx, __shfl_xor(mx, 2));
      mx = fmaxf(mx, __shfl_xor(mx, 4));  mx = fmaxf(mx, __shfl_xor(mx, 8));
      mx = fmaxf(mx, __shfl_xor(mx, 16));
      float e = __expf(ln - mx);
      float se = e;
      se += __shfl_xor(se, 1); se += __shfl_xor(se, 2); se += __shfl_xor(se, 4);
      se += __shfl_xor(se, 8); se += __shfl_xor(se, 16);
      if (l < 32) wout[(size_t)tB * 32 + l] = e / se;
    }
  }
}

// ---------------------------------------------------------------------------
// Kernel 2: EXACT R9 champion (125.4us, bit-stable across R13/R14/R15):
// 2 features/barrier, 4-buf a_lds, deferred finalize, LDS atomicAdd +
// 3-buffer sred, 36 carried regs.
// ---------------------------------------------------------------------------
__global__ __launch_bounds__(512, 4) void k_main(
    const float* __restrict__ x,
    const float* __restrict__ fw1, const float* __restrict__ fb1,
    const unsigned short* __restrict__ bfrag, const float* __restrict__ scal,
    const float* __restrict__ wts, float* __restrict__ out)
{
  __shared__ __align__(16) unsigned short a_lds[4][TOKB * 128]; // 4 x 8 KB
  __shared__ __align__(16) float x_lds[FDIM * TOKB];            // [f][t] 4 KB
  __shared__ __align__(16) float w_lds[FDIM * TOKB];            // [f][t] 4 KB
  __shared__ __align__(16) float sred[3][2][2][TOKB];           // 1.5 KB

  const int tid = threadIdx.x;
  const int w   = tid >> 6;
  const int l   = tid & 63;
  const int tk  = l & 15;        // token within a 16-token tile
  const int rg  = l >> 4;        // row-group: lane's 4 h's = h0..h0+3
  const int t0  = blockIdx.x * TOKB;
  const int h0  = w * 16 + rg * 4;
  const int st  = tid >> 4;            // staging token 0..31
  const int sk  = (tid & 15) * 8;      // staging k 0..120
  const int stg_byte = (st * 256 + sk * 2) ^ ((st & 7) << 4);

  // prologue: stage x,w transposed to [f][t]; zero all sred buffers
  {
    float2v xv = *(const float2v*)(x   + (size_t)t0 * FDIM + tid * 2);
    float2v wv = *(const float2v*)(wts + (size_t)t0 * FDIM + tid * 2);
#pragma unroll
    for (int e = 0; e < 2; ++e) {
      int flat = tid * 2 + e;
      int tt = flat >> 5, ff = flat & 31;
      x_lds[ff * TOKB + tt] = xv[e];
      w_lds[ff * TOKB + tt] = wv[e];
    }
    if (tid < 384) ((float*)sred)[tid] = 0.f;
  }

  float4v oa0 = (float4v){0.f, 0.f, 0.f, 0.f};
  float4v oa1 = (float4v){0.f, 0.f, 0.f, 0.f};
  // carried prev-pair state (feature A = even, B = odd of the previous pair)
  float4v pyA0 = oa0, pyA1 = oa0, pyB0 = oa0, pyB1 = oa0;
  float4v plgA = oa0, plbA = oa0, plgB = oa0, plbB = oa0;
  float pwtA0 = 0.f, pwtA1 = 0.f, pwtB0 = 0.f, pwtB1 = 0.f;

  __syncthreads();   // x_lds/w_lds/sred ready

  int p = 0;   // pair-buffer index = k % 3
#pragma unroll 1
  for (int k = 0; k < FDIM / 2; ++k) {
    const int g    = 2 * k;
    const int bufp = (k & 1) * 2;

    // ---- A-frags for feature g (issued early; consumed after barrier) ----
    short8 aV[4], aG[4];
    {
      const unsigned short* bb = bfrag + (((size_t)g * 8 + w) * 8) * 512 + (size_t)l * 8;
#pragma unroll
      for (int ks = 0; ks < 4; ++ks) {
        aV[ks] = *(const short8*)(bb + (size_t)ks * 512);
        aG[ks] = *(const short8*)(bb + (size_t)(4 + ks) * 512);
      }
    }

    // ---- stage h1(g) -> a_lds[bufp] ----
    {
      float xf = x_lds[g * TOKB + st];
      float4v w1a = *(const float4v*)(fw1 + g * HDIM + sk);
      float4v w1b = *(const float4v*)(fw1 + g * HDIM + sk + 4);
      float4v b1a = *(const float4v*)(fb1 + g * HDIM + sk);
      float4v b1b = *(const float4v*)(fb1 + g * HDIM + sk + 4);
      uint4v pk;
      pk[0] = cvtpk(elu_f(fmaf(xf, w1a[0], b1a[0])),
                    elu_f(fmaf(xf, w1a[1], b1a[1])));
      pk[1] = cvtpk(elu_f(fmaf(xf, w1a[2], b1a[2])),
                    elu_f(fmaf(xf, w1a[3], b1a[3])));
      pk[2] = cvtpk(elu_f(fmaf(xf, w1b[0], b1b[0])),
                    elu_f(fmaf(xf, w1b[1], b1b[1])));
      pk[3] = cvtpk(elu_f(fmaf(xf, w1b[2], b1b[2])),
                    elu_f(fmaf(xf, w1b[3], b1b[3])));
      *(uint4v*)((char*)a_lds[bufp] + stg_byte) = pk;
    }
    // ---- stage h1(g+1) -> a_lds[bufp+1] ----
    {
      float xf = x_lds[(g + 1) * TOKB + st];
      float4v w1a = *(const float4v*)(fw1 + (g + 1) * HDIM + sk);
      float4v w1b = *(const float4v*)(fw1 + (g + 1) * HDIM + sk + 4);
      float4v b1a = *(const float4v*)(fb1 + (g + 1) * HDIM + sk);
      float4v b1b = *(const float4v*)(fb1 + (g + 1) * HDIM + sk + 4);
      uint4v pk;
      pk[0] = cvtpk(elu_f(fmaf(xf, w1a[0], b1a[0])),
                    elu_f(fmaf(xf, w1a[1], b1a[1])));
      pk[1] = cvtpk(elu_f(fmaf(xf, w1a[2], b1a[2])),
                    elu_f(fmaf(xf, w1a[3], b1a[3])));
      pk[2] = cvtpk(elu_f(fmaf(xf, w1b[0], b1b[0])),
                    elu_f(fmaf(xf, w1b[1], b1b[1])));
      pk[3] = cvtpk(elu_f(fmaf(xf, w1b[2], b1b[2])),
                    elu_f(fmaf(xf, w1b[3], b1b[3])));
      *(uint4v*)((char*)a_lds[bufp + 1] + stg_byte) = pk;
    }

    __syncthreads();   // B_k: buffers ready; atomics of pair k-1 visible

    // ---- deferred LN finalize for pair k-1 ----
    if (k > 0) {
      const int pp = (p == 0) ? 2 : p - 1;
      {   // feature A = 2(k-1)
        float sA  = sred[pp][0][0][tk],      ssA = sred[pp][0][1][tk];
        float sB  = sred[pp][0][0][16 + tk], ssB = sred[pp][0][1][16 + tk];
        float m0 = sA * (1.f / 128.f);
        float m1 = sB * (1.f / 128.f);
        float v0 = fmaf(-m0, m0, ssA * (1.f / 128.f));
        float v1 = fmaf(-m1, m1, ssB * (1.f / 128.f));
        float rw0 = rsqrtf(v0 + 1e-5f) * pwtA0;
        float rw1 = rsqrtf(v1 + 1e-5f) * pwtA1;
#pragma unroll
        for (int i = 0; i < 4; ++i) {
          oa0[i] = fmaf((pyA0[i] - m0) * rw0, plgA[i], fmaf(pwtA0, plbA[i], oa0[i]));
          oa1[i] = fmaf((pyA1[i] - m1) * rw1, plgA[i], fmaf(pwtA1, plbA[i], oa1[i]));
        }
      }
      {   // feature B = 2(k-1)+1
        float sA  = sred[pp][1][0][tk],      ssA = sred[pp][1][1][tk];
        float sB  = sred[pp][1][0][16 + tk], ssB = sred[pp][1][1][16 + tk];
        float m0 = sA * (1.f / 128.f);
        float m1 = sB * (1.f / 128.f);
        float v0 = fmaf(-m0, m0, ssA * (1.f / 128.f));
        float v1 = fmaf(-m1, m1, ssB * (1.f / 128.f));
        float rw0 = rsqrtf(v0 + 1e-5f) * pwtB0;
        float rw1 = rsqrtf(v1 + 1e-5f) * pwtB1;
#pragma unroll
        for (int i = 0; i < 4; ++i) {
          oa0[i] = fmaf((pyB0[i] - m0) * rw0, plgB[i], fmaf(pwtB0, plbB[i], oa0[i]));
          oa1[i] = fmaf((pyB1[i] - m1) * rw1, plgB[i], fmaf(pwtB1, plbB[i], oa1[i]));
        }
      }
    }

    // ================= feature g =================
    {
      const float* sp = scal + (size_t)g * 640 + h0;
      float4v bcv = *(const float4v*)(sp);
      float4v bcg = *(const float4v*)(sp + 128);
      float4v fs4 = *(const float4v*)(sp + 256);
      float4v lg4 = *(const float4v*)(sp + 384);
      float4v lb4 = *(const float4v*)(sp + 512);

      float4v av0 = (float4v){0.f,0.f,0.f,0.f}, ag0 = av0, av1 = av0, ag1 = av0;
#pragma unroll
      for (int ks = 0; ks < 4; ++ks) {
        int b0 = tk * 256 + (ks * 32 + rg * 8) * 2;
        b0 ^= (tk & 7) << 4;
        short8 hf0 = *(const short8*)((const char*)a_lds[bufp] + b0);
        int b1 = (16 + tk) * 256 + (ks * 32 + rg * 8) * 2;
        b1 ^= (tk & 7) << 4;
        short8 hf1 = *(const short8*)((const char*)a_lds[bufp] + b1);
        av0 = __builtin_amdgcn_mfma_f32_16x16x32_bf16(aV[ks], hf0, av0, 0, 0, 0);
        ag0 = __builtin_amdgcn_mfma_f32_16x16x32_bf16(aG[ks], hf0, ag0, 0, 0, 0);
        av1 = __builtin_amdgcn_mfma_f32_16x16x32_bf16(aV[ks], hf1, av1, 0, 0, 0);
        ag1 = __builtin_amdgcn_mfma_f32_16x16x32_bf16(aG[ks], hf1, ag1, 0, 0, 0);
      }

      float xt0 = x_lds[g * TOKB + tk],      wt0 = w_lds[g * TOKB + tk];
      float xt1 = x_lds[g * TOKB + 16 + tk], wt1 = w_lds[g * TOKB + 16 + tk];
      float s0 = 0.f, ss0 = 0.f, s1 = 0.f, ss1 = 0.f;
#pragma unroll
      for (int i = 0; i < 4; ++i) {
        float ya = fmaf(xt0, fs4[i], (av0[i] + bcv[i]) * sigm_f(ag0[i] + bcg[i]));
        float yb = fmaf(xt1, fs4[i], (av1[i] + bcv[i]) * sigm_f(ag1[i] + bcg[i]));
        pyA0[i] = ya; pyA1[i] = yb;
        s0 += ya; ss0 = fmaf(ya, ya, ss0);
        s1 += yb; ss1 = fmaf(yb, yb, ss1);
      }
      s0  += __shfl_xor(s0, 16);  s0  += __shfl_xor(s0, 32);
      ss0 += __shfl_xor(ss0, 16); ss0 += __shfl_xor(ss0, 32);
      s1  += __shfl_xor(s1, 16);  s1  += __shfl_xor(s1, 32);
      ss1 += __shfl_xor(ss1, 16); ss1 += __shfl_xor(ss1, 32);
      if (rg == 0) {
        atomicAdd(&sred[p][0][0][tk], s0);
        atomicAdd(&sred[p][0][0][16 + tk], s1);
      } else if (rg == 1) {
        atomicAdd(&sred[p][0][1][tk], ss0);
        atomicAdd(&sred[p][0][1][16 + tk], ss1);
      }
      plgA = lg4; plbA = lb4; pwtA0 = wt0; pwtA1 = wt1;
    }

    // ---- A-frags for feature g+1 (reuse aV/aG registers) ----
    {
      const unsigned short* bb = bfrag + (((size_t)(g + 1) * 8 + w) * 8) * 512 + (size_t)l * 8;
#pragma unroll
      for (int ks = 0; ks < 4; ++ks) {
        aV[ks] = *(const short8*)(bb + (size_t)ks * 512);
        aG[ks] = *(const short8*)(bb + (size_t)(4 + ks) * 512);
      }
    }

    // ================= feature g+1 =================
    {
      const float* sp = scal + (size_t)(g + 1) * 640 + h0;
      float4v bcv = *(const float4v*)(sp);
      float4v bcg = *(const float4v*)(sp + 128);
      float4v fs4 = *(const float4v*)(sp + 256);
      float4v lg4 = *(const float4v*)(sp + 384);
      float4v lb4 = *(const float4v*)(sp + 512);

      float4v av0 = (float4v){0.f,0.f,0.f,0.f}, ag0 = av0, av1 = av0, ag1 = av0;
#pragma unroll
      for (int ks = 0; ks < 4; ++ks) {
        int b0 = tk * 256 + (ks * 32 + rg * 8) * 2;
        b0 ^= (tk & 7) << 4;
        short8 hf0 = *(const short8*)((const char*)a_lds[bufp + 1] + b0);
        int b1 = (16 + tk) * 256 + (ks * 32 + rg * 8) * 2;
        b1 ^= (tk & 7) << 4;
        short8 hf1 = *(const short8*)((const char*)a_lds[bufp + 1] + b1);
        av0 = __builtin_amdgcn_mfma_f32_16x16x32_bf16(aV[ks], hf0, av0, 0, 0, 0);
        ag0 = __builtin_amdgcn_mfma_f32_16x16x32_bf16(aG[ks], hf0, ag0, 0, 0, 0);
        av1 = __builtin_amdgcn_mfma_f32_16x16x32_bf16(aV[ks], hf1, av1, 0, 0, 0);
        ag1 = __builtin_amdgcn_mfma_f32_16x16x32_bf16(aG[ks], hf1, ag1, 0, 0, 0);
      }

      float xt0 = x_lds[(g + 1) * TOKB + tk],      wt0 = w_lds[(g + 1) * TOKB + tk];
      float xt1 = x_lds[(g + 1) * TOKB + 16 + tk], wt1 = w_lds[(g + 1) * TOKB + 16 + tk];
      float s0 = 0.f, ss0 = 0.f, s1 = 0.f, ss1 = 0.f;
#pragma unroll
      for (int i = 0; i < 4; ++i) {
        float ya = fmaf(xt0, fs4[i], (av0[i] + bcv[i]) * sigm_f(ag0[i] + bcg[i]));
        float yb = fmaf(xt1, fs4[i], (av1[i] + bcv[i]) * sigm_f(ag1[i] + bcg[i]));
        pyB0[i] = ya; pyB1[i] = yb;
        s0 += ya; ss0 = fmaf(ya, ya, ss0);
        s1 += yb; ss1 = fmaf(yb, yb, ss1);
      }
      s0  += __shfl_xor(s0, 16);  s0  += __shfl_xor(s0, 32);
      ss0 += __shfl_xor(ss0, 16); ss0 += __shfl_xor(ss0, 32);
      s1  += __shfl_xor(s1, 16);  s1  += __shfl_xor(s1, 32);
      ss1 += __shfl_xor(ss1, 16); ss1 += __shfl_xor(ss1, 32);
      if (rg == 0) {
        atomicAdd(&sred[p][1][0][tk], s0);
        atomicAdd(&sred[p][1][0][16 + tk], s1);
      } else if (rg == 1) {
        atomicAdd(&sred[p][1][1][tk], ss0);
        atomicAdd(&sred[p][1][1][16 + tk], ss1);
      }
      plgB = lg4; plbB = lb4; pwtB0 = wt0; pwtB1 = wt1;
    }

    // zero the pair-buffer used at iter k+1 (barrier-separated both ways)
    {
      const int pn = (p == 2) ? 0 : p + 1;
      if (tid < 128) ((float*)(sred[pn]))[tid] = 0.f;
      p = pn;
    }
  }

  // ---- tail: finalize pair 15 (features 30, 31) ----
  __syncthreads();
  {
    const int pp = (p == 0) ? 2 : p - 1;
    {
      float sA  = sred[pp][0][0][tk],      ssA = sred[pp][0][1][tk];
      float sB  = sred[pp][0][0][16 + tk], ssB = sred[pp][0][1][16 + tk];
      float m0 = sA * (1.f / 128.f);
      float m1 = sB * (1.f / 128.f);
      float v0 = fmaf(-m0, m0, ssA * (1.f / 128.f));
      float v1 = fmaf(-m1, m1, ssB * (1.f / 128.f));
      float rw0 = rsqrtf(v0 + 1e-5f) * pwtA0;
      float rw1 = rsqrtf(v1 + 1e-5f) * pwtA1;
#pragma unroll
      for (int i = 0; i < 4; ++i) {
        oa0[i] = fmaf((pyA0[i] - m0) * rw0, plgA[i], fmaf(pwtA0, plbA[i], oa0[i]));
        oa1[i] = fmaf((pyA1[i] - m1) * rw1, plgA[i], fmaf(pwtA1, plbA[i], oa1[i]));
      }
    }
    {
      float sA  = sred[pp][1][0][tk],      ssA = sred[pp][1][1][tk];
      float sB  = sred[pp][1][0][16 + tk], ssB = sred[pp][1][1][16 + tk];
      float m0 = sA * (1.f / 128.f);
      float m1 = sB * (1.f / 128.f);
      float v0 = fmaf(-m0, m0, ssA * (1.f / 128.f));
      float v1 = fmaf(-m1, m1, ssB * (1.f / 128.f));
      float rw0 = rsqrtf(v0 + 1e-5f) * pwtB0;
      float rw1 = rsqrtf(v1 + 1e-5f) * pwtB1;
#pragma unroll
      for (int i = 0; i < 4; ++i) {
        oa0[i] = fmaf((pyB0[i] - m0) * rw0, plgB[i], fmaf(pwtB0, plbB[i], oa0[i]));
        oa1[i] = fmaf((pyB1[i] - m1) * rw1, plgB[i], fmaf(pwtB1, plbB[i], oa1[i]));
      }
    }
  }

  // ---- store: per lane 2 x 16B contiguous ----
  *(float4v*)(out + (size_t)(t0 + tk) * HDIM + h0)      = oa0;
  *(float4v*)(out + (size_t)(t0 + 16 + tk) * HDIM + h0) = oa1;
}

extern "C" void kernel_launch(void* const* d_in, const int* in_sizes, int n_in,
                              void* d_out, int out_size, void* d_ws, size_t ws_size,
                              hipStream_t stream) {
  const float* x      = (const float*)d_in[0];
  const float* fw1    = (const float*)d_in[1];
  const float* fb1    = (const float*)d_in[2];
  const float* fw2    = (const float*)d_in[3];
  const float* fb2    = (const float*)d_in[4];
  const float* fglu_w = (const float*)d_in[5];
  const float* fglu_b = (const float*)d_in[6];
  const float* fskip  = (const float*)d_in[7];
  const float* fln_g  = (const float*)d_in[8];
  const float* fln_b  = (const float*)d_in[9];
  const float* ww1    = (const float*)d_in[10];
  const float* wb1    = (const float*)d_in[11];
  const float* ww2    = (const float*)d_in[12];
  const float* wb2    = (const float*)d_in[13];
  const float* wglu_w = (const float*)d_in[14];
  const float* wglu_b = (const float*)d_in[15];
  const float* wln_g  = (const float*)d_in[16];
  const float* wln_b  = (const float*)d_in[17];

  float* outp = (float*)d_out;
  float* wout = outp + (size_t)NTOK * HDIM;

  unsigned short* bfrag = (unsigned short*)d_ws;                  // 2 MiB bf16
  float* scal = (float*)((char*)d_ws + (size_t)2 * 1024 * 1024);  // 80 KiB f32

  k_pw<<<dim3(128 + NTOK / 8), dim3(256), 0, stream>>>(
      x, fw2, fb2, fglu_w, fglu_b, fskip, fln_g, fln_b,
      ww1, wb1, ww2, wb2, wglu_w, wglu_b, wln_g, wln_b,
      bfrag, scal, wout);
  k_main<<<dim3(NTOK / TOKB), dim3(512), 0, stream>>>(
      x, fw1, fb1, bfrag, scal, wout, outp);
}

// Round 17
// 133.805 us; speedup vs baseline: 1.0785x; 1.0342x over previous
//
#include <hip/hip_runtime.h>
#include <cstdint>
#include <cstddef>

#define NTOK 16384
#define FDIM 32
#define HDIM 128
#define TOKB 32

typedef __attribute__((ext_vector_type(8))) short short8;     // bf16x8 MFMA frag
typedef __attribute__((ext_vector_type(4))) float float4v;
typedef __attribute__((ext_vector_type(2))) float float2v;
typedef __attribute__((ext_vector_type(4))) unsigned int uint4v;

__device__ __forceinline__ float elu_f(float x)  { return x > 0.f ? x : __expf(x) - 1.f; }
__device__ __forceinline__ float sigm_f(float x) { return 1.f / (1.f + __expf(-x)); }

// fp32 -> bf16 RNE
__device__ __forceinline__ unsigned int f2bf(float f) {
  unsigned int u = __float_as_uint(f);
  u += 0x7FFFu + ((u >> 16) & 1u);
  return u >> 16;
}
// packed fp32x2 -> bf16x2 in one VALU op (RNE)
__device__ __forceinline__ unsigned int cvtpk(float lo, float hi) {
  unsigned int r;
  asm("v_cvt_pk_bf16_f32 %0, %1, %2" : "=v"(r) : "v"(lo), "v"(hi));
  return r;
}

// ---------------------------------------------------------------------------
// Kernel 1 v17:
//  Blocks [0,256): fcomb = fw2 @ fglu_w, 16 SOURCE ROWS PER BLOCK (R12-
//    validated indexing: ks = ks8>>1, gg base = (ks8&1)*2) — halves the
//    critical-path block duration vs the 128-block form; same TILE-MAJOR
//    bfrag layout + scal pack.
//  Blocks [256, 256+2048): weight-GRN + softmax, 2 tokens per wave (R14
//    champion config — measured optimum of the ILP/occupancy trade).
// ---------------------------------------------------------------------------
__global__ __launch_bounds__(256) void k_pw(
    const float* __restrict__ x,
    const float* __restrict__ fw2, const float* __restrict__ fb2,
    const float* __restrict__ fglu_w, const float* __restrict__ fglu_b,
    const float* __restrict__ fskip, const float* __restrict__ flng,
    const float* __restrict__ flnb,
    const float* __restrict__ ww1, const float* __restrict__ wb1,
    const float* __restrict__ ww2, const float* __restrict__ wb2,
    const float* __restrict__ wglu_w, const float* __restrict__ wglu_b,
    const float* __restrict__ wln_g, const float* __restrict__ wln_b,
    unsigned short* __restrict__ bfrag, float* __restrict__ scal,
    float* __restrict__ wout)
{
  __shared__ __align__(16) float smem[4096];
  const int tid = threadIdx.x;

  if (blockIdx.x < 256) {
    // -------- fcomb, 16 rows/block (R12-validated index form) --------
    const int f   = blockIdx.x >> 3;
    const int ks8 = blockIdx.x & 7;          // 16-row chunk of k
    const float* src = fw2 + ((size_t)f * 128 + ks8 * 16) * 128;
    for (int i = 0; i < 2; ++i) {
      int vi = tid + i * 256;
      *(float4v*)&smem[vi * 4] = *(const float4v*)&src[vi * 4];
    }
    __syncthreads();

    const int o2 = tid;
    float acc[16];
#pragma unroll
    for (int kk = 0; kk < 16; ++kk) acc[kk] = 0.f;
    float bacc = 0.f;

    for (int o = 0; o < 128; o += 4) {
      float gv0 = fglu_w[((size_t)f * 128 + o + 0) * 256 + o2];
      float gv1 = fglu_w[((size_t)f * 128 + o + 1) * 256 + o2];
      float gv2 = fglu_w[((size_t)f * 128 + o + 2) * 256 + o2];
      float gv3 = fglu_w[((size_t)f * 128 + o + 3) * 256 + o2];
      bacc += fb2[f * 128 + o + 0] * gv0 + fb2[f * 128 + o + 1] * gv1
            + fb2[f * 128 + o + 2] * gv2 + fb2[f * 128 + o + 3] * gv3;
#pragma unroll
      for (int kk = 0; kk < 16; ++kk) {
        float4v a4 = *(const float4v*)&smem[kk * 128 + o];
        acc[kk] += a4[0] * gv0 + a4[1] * gv1 + a4[2] * gv2 + a4[3] * gv3;
      }
    }

    const int type = o2 >> 7;
    const int h    = o2 & 127;
    const int w2   = h >> 4;
    const int r    = h & 15;
    const int ks   = ks8 >> 1;
    const int ggb  = (ks8 & 1) * 2;
    const size_t tbase = ((((size_t)f * 8 + w2) * 2 + type) * 4 + ks) * 512;
#pragma unroll
    for (int g2 = 0; g2 < 2; ++g2) {
      uint4v pk;
      pk[0] = f2bf(acc[g2 * 8 + 0]) | (f2bf(acc[g2 * 8 + 1]) << 16);
      pk[1] = f2bf(acc[g2 * 8 + 2]) | (f2bf(acc[g2 * 8 + 3]) << 16);
      pk[2] = f2bf(acc[g2 * 8 + 4]) | (f2bf(acc[g2 * 8 + 5]) << 16);
      pk[3] = f2bf(acc[g2 * 8 + 6]) | (f2bf(acc[g2 * 8 + 7]) << 16);
      *(uint4v*)(bfrag + tbase + (size_t)(r + (ggb + g2) * 16) * 8) = pk;
    }
    if (ks8 == 0) {
      scal[f * 640 + type * 128 + h] = bacc + fglu_b[f * 256 + o2];
      if (type == 0) {
        scal[f * 640 + 256 + h] = fskip[f * 128 + h];
        scal[f * 640 + 384 + h] = flng[f * 128 + h];
        scal[f * 640 + 512 + h] = flnb[f * 128 + h];
      }
    }

  } else {
    // ------- weight-GRN + softmax: 2 tokens per wave (2-chain ILP) -------
    const int bid = blockIdx.x - 256;
    const int wv  = tid >> 6;
    const int l   = tid & 63;
    const int tA  = bid * 8 + wv * 2;
    const int tB  = tA + 1;
    float* S = smem + wv * 512;   // [0..192) token A, [256..448) token B

    float xvA = x[(size_t)tA * 32 + (l & 31)];
    float xvB = x[(size_t)tB * 32 + (l & 31)];
    if (l < 32) { S[l] = xvA; S[256 + l] = xvB; }
    float a0A = wb1[l], a1A = wb1[l + 64];
    float a0B = a0A,    a1B = a1A;
    __syncthreads();
    for (int f2 = 0; f2 < 32; ++f2) {
      float w1a = ww1[f2 * 128 + l];
      float w1b = ww1[f2 * 128 + l + 64];
      float xfA = S[f2], xfB = S[256 + f2];
      a0A = fmaf(xfA, w1a, a0A);  a1A = fmaf(xfA, w1b, a1A);
      a0B = fmaf(xfB, w1a, a0B);  a1B = fmaf(xfB, w1b, a1B);
    }
    a0A = elu_f(a0A); a1A = elu_f(a1A);
    a0B = elu_f(a0B); a1B = elu_f(a1B);
    S[32 + l] = a0A;       S[32 + l + 64] = a1A;
    S[256 + 32 + l] = a0B; S[256 + 32 + l + 64] = a1B;
    __syncthreads();

    const int o    = l & 31;
    const int half = l >> 5;
    float bA = 0.f, bB = 0.f;
    for (int hh = 0; hh < 64; ++hh) {
      float w2v = ww2[(half * 64 + hh) * 32 + o];
      bA = fmaf(S[32 + half * 64 + hh], w2v, bA);
      bB = fmaf(S[256 + 32 + half * 64 + hh], w2v, bB);
    }
    bA += __shfl_xor(bA, 32);  bA += wb2[o];
    bB += __shfl_xor(bB, 32);  bB += wb2[o];
    S[160 + o] = bA;
    S[256 + 160 + o] = bB;
    __syncthreads();

    float gA = wglu_b[l], gB = wglu_b[l];
    for (int o2i = 0; o2i < 32; ++o2i) {
      float wv2 = wglu_w[o2i * 64 + l];
      gA = fmaf(S[160 + o2i], wv2, gA);
      gB = fmaf(S[256 + 160 + o2i], wv2, gB);
    }

    // GLU + skip + LN + softmax (token A then token B)
    {
      float gate = __shfl_xor(gA, 32);
      float y = gA * sigm_f(gate) + xvA;
      float s = y;
      s += __shfl_xor(s, 1); s += __shfl_xor(s, 2); s += __shfl_xor(s, 4);
      s += __shfl_xor(s, 8); s += __shfl_xor(s, 16);
      float mean = s * (1.f / 32.f);
      float d = y - mean;
      float ss = d * d;
      ss += __shfl_xor(ss, 1); ss += __shfl_xor(ss, 2); ss += __shfl_xor(ss, 4);
      ss += __shfl_xor(ss, 8); ss += __shfl_xor(ss, 16);
      float rstd = rsqrtf(ss * (1.f / 32.f) + 1e-5f);
      float ln = d * rstd * wln_g[o] + wln_b[o];
      float mx = ln;
      mx = fmaxf(mx, __shfl_xor(mx, 1));  mx = fmaxf(mx, __shfl_xor(mx, 2));
      mx = fmaxf(mx, __shfl_xor(mx, 4));  mx = fmaxf(mx, __shfl_xor(mx, 8));
      mx = fmaxf(mx, __shfl_xor(mx, 16));
      float e = __expf(ln - mx);
      float se = e;
      se += __shfl_xor(se, 1); se += __shfl_xor(se, 2); se += __shfl_xor(se, 4);
      se += __shfl_xor(se, 8); se += __shfl_xor(se, 16);
      if (l < 32) wout[(size_t)tA * 32 + l] = e / se;
    }
    {
      float gate = __shfl_xor(gB, 32);
      float y = gB * sigm_f(gate) + xvB;
      float s = y;
      s += __shfl_xor(s, 1); s += __shfl_xor(s, 2); s += __shfl_xor(s, 4);
      s += __shfl_xor(s, 8); s += __shfl_xor(s, 16);
      float mean = s * (1.f / 32.f);
      float d = y - mean;
      float ss = d * d;
      ss += __shfl_xor(ss, 1); ss += __shfl_xor(ss, 2); ss += __shfl_xor(ss, 4);
      ss += __shfl_xor(ss, 8); ss += __shfl_xor(ss, 16);
      float rstd = rsqrtf(ss * (1.f / 32.f) + 1e-5f);
      float ln = d * rstd * wln_g[o] + wln_b[o];
      float mx = ln;
      mx = fmaxf(mx, __shfl_xor(mx, 1));  mx = fmaxf(mx, __shfl_xor(mx, 2));
      mx = fmaxf(mx, __shfl_xor(mx, 4));  mx = fmaxf(mx, __shfl_xor(mx, 8));
      mx = fmaxf(mx, __shfl_xor(mx, 16));
      float e = __expf(ln - mx);
      float se = e;
      se += __shfl_xor(se, 1); se += __shfl_xor(se, 2); se += __shfl_xor(se, 4);
      se += __shfl_xor(se, 8); se += __shfl_xor(se, 16);
      if (l < 32) wout[(size_t)tB * 32 + l] = e / se;
    }
  }
}

// ---------------------------------------------------------------------------
// Kernel 2: EXACT R9 champion (125.4us, bit-stable across 5 rounds):
// 2 features/barrier, 4-buf a_lds, deferred finalize, LDS atomicAdd +
// 3-buffer sred, 36 carried regs.
// ---------------------------------------------------------------------------
__global__ __launch_bounds__(512, 4) void k_main(
    const float* __restrict__ x,
    const float* __restrict__ fw1, const float* __restrict__ fb1,
    const unsigned short* __restrict__ bfrag, const float* __restrict__ scal,
    const float* __restrict__ wts, float* __restrict__ out)
{
  __shared__ __align__(16) unsigned short a_lds[4][TOKB * 128]; // 4 x 8 KB
  __shared__ __align__(16) float x_lds[FDIM * TOKB];            // [f][t] 4 KB
  __shared__ __align__(16) float w_lds[FDIM * TOKB];            // [f][t] 4 KB
  __shared__ __align__(16) float sred[3][2][2][TOKB];           // 1.5 KB

  const int tid = threadIdx.x;
  const int w   = tid >> 6;
  const int l   = tid & 63;
  const int tk  = l & 15;        // token within a 16-token tile
  const int rg  = l >> 4;        // row-group: lane's 4 h's = h0..h0+3
  const int t0  = blockIdx.x * TOKB;
  const int h0  = w * 16 + rg * 4;
  const int st  = tid >> 4;            // staging token 0..31
  const int sk  = (tid & 15) * 8;      // staging k 0..120
  const int stg_byte = (st * 256 + sk * 2) ^ ((st & 7) << 4);

  // prologue: stage x,w transposed to [f][t]; zero all sred buffers
  {
    float2v xv = *(const float2v*)(x   + (size_t)t0 * FDIM + tid * 2);
    float2v wv = *(const float2v*)(wts + (size_t)t0 * FDIM + tid * 2);
#pragma unroll
    for (int e = 0; e < 2; ++e) {
      int flat = tid * 2 + e;
      int tt = flat >> 5, ff = flat & 31;
      x_lds[ff * TOKB + tt] = xv[e];
      w_lds[ff * TOKB + tt] = wv[e];
    }
    if (tid < 384) ((float*)sred)[tid] = 0.f;
  }

  float4v oa0 = (float4v){0.f, 0.f, 0.f, 0.f};
  float4v oa1 = (float4v){0.f, 0.f, 0.f, 0.f};
  // carried prev-pair state (feature A = even, B = odd of the previous pair)
  float4v pyA0 = oa0, pyA1 = oa0, pyB0 = oa0, pyB1 = oa0;
  float4v plgA = oa0, plbA = oa0, plgB = oa0, plbB = oa0;
  float pwtA0 = 0.f, pwtA1 = 0.f, pwtB0 = 0.f, pwtB1 = 0.f;

  __syncthreads();   // x_lds/w_lds/sred ready

  int p = 0;   // pair-buffer index = k % 3
#pragma unroll 1
  for (int k = 0; k < FDIM / 2; ++k) {
    const int g    = 2 * k;
    const int bufp = (k & 1) * 2;

    // ---- A-frags for feature g (issued early; consumed after barrier) ----
    short8 aV[4], aG[4];
    {
      const unsigned short* bb = bfrag + (((size_t)g * 8 + w) * 8) * 512 + (size_t)l * 8;
#pragma unroll
      for (int ks = 0; ks < 4; ++ks) {
        aV[ks] = *(const short8*)(bb + (size_t)ks * 512);
        aG[ks] = *(const short8*)(bb + (size_t)(4 + ks) * 512);
      }
    }

    // ---- stage h1(g) -> a_lds[bufp] ----
    {
      float xf = x_lds[g * TOKB + st];
      float4v w1a = *(const float4v*)(fw1 + g * HDIM + sk);
      float4v w1b = *(const float4v*)(fw1 + g * HDIM + sk + 4);
      float4v b1a = *(const float4v*)(fb1 + g * HDIM + sk);
      float4v b1b = *(const float4v*)(fb1 + g * HDIM + sk + 4);
      uint4v pk;
      pk[0] = cvtpk(elu_f(fmaf(xf, w1a[0], b1a[0])),
                    elu_f(fmaf(xf, w1a[1], b1a[1])));
      pk[1] = cvtpk(elu_f(fmaf(xf, w1a[2], b1a[2])),
                    elu_f(fmaf(xf, w1a[3], b1a[3])));
      pk[2] = cvtpk(elu_f(fmaf(xf, w1b[0], b1b[0])),
                    elu_f(fmaf(xf, w1b[1], b1b[1])));
      pk[3] = cvtpk(elu_f(fmaf(xf, w1b[2], b1b[2])),
                    elu_f(fmaf(xf, w1b[3], b1b[3])));
      *(uint4v*)((char*)a_lds[bufp] + stg_byte) = pk;
    }
    // ---- stage h1(g+1) -> a_lds[bufp+1] ----
    {
      float xf = x_lds[(g + 1) * TOKB + st];
      float4v w1a = *(const float4v*)(fw1 + (g + 1) * HDIM + sk);
      float4v w1b = *(const float4v*)(fw1 + (g + 1) * HDIM + sk + 4);
      float4v b1a = *(const float4v*)(fb1 + (g + 1) * HDIM + sk);
      float4v b1b = *(const float4v*)(fb1 + (g + 1) * HDIM + sk + 4);
      uint4v pk;
      pk[0] = cvtpk(elu_f(fmaf(xf, w1a[0], b1a[0])),
                    elu_f(fmaf(xf, w1a[1], b1a[1])));
      pk[1] = cvtpk(elu_f(fmaf(xf, w1a[2], b1a[2])),
                    elu_f(fmaf(xf, w1a[3], b1a[3])));
      pk[2] = cvtpk(elu_f(fmaf(xf, w1b[0], b1b[0])),
                    elu_f(fmaf(xf, w1b[1], b1b[1])));
      pk[3] = cvtpk(elu_f(fmaf(xf, w1b[2], b1b[2])),
                    elu_f(fmaf(xf, w1b[3], b1b[3])));
      *(uint4v*)((char*)a_lds[bufp + 1] + stg_byte) = pk;
    }

    __syncthreads();   // B_k: buffers ready; atomics of pair k-1 visible

    // ---- deferred LN finalize for pair k-1 ----
    if (k > 0) {
      const int pp = (p == 0) ? 2 : p - 1;
      {   // feature A = 2(k-1)
        float sA  = sred[pp][0][0][tk],      ssA = sred[pp][0][1][tk];
        float sB  = sred[pp][0][0][16 + tk], ssB = sred[pp][0][1][16 + tk];
        float m0 = sA * (1.f / 128.f);
        float m1 = sB * (1.f / 128.f);
        float v0 = fmaf(-m0, m0, ssA * (1.f / 128.f));
        float v1 = fmaf(-m1, m1, ssB * (1.f / 128.f));
        float rw0 = rsqrtf(v0 + 1e-5f) * pwtA0;
        float rw1 = rsqrtf(v1 + 1e-5f) * pwtA1;
#pragma unroll
        for (int i = 0; i < 4; ++i) {
          oa0[i] = fmaf((pyA0[i] - m0) * rw0, plgA[i], fmaf(pwtA0, plbA[i], oa0[i]));
          oa1[i] = fmaf((pyA1[i] - m1) * rw1, plgA[i], fmaf(pwtA1, plbA[i], oa1[i]));
        }
      }
      {   // feature B = 2(k-1)+1
        float sA  = sred[pp][1][0][tk],      ssA = sred[pp][1][1][tk];
        float sB  = sred[pp][1][0][16 + tk], ssB = sred[pp][1][1][16 + tk];
        float m0 = sA * (1.f / 128.f);
        float m1 = sB * (1.f / 128.f);
        float v0 = fmaf(-m0, m0, ssA * (1.f / 128.f));
        float v1 = fmaf(-m1, m1, ssB * (1.f / 128.f));
        float rw0 = rsqrtf(v0 + 1e-5f) * pwtB0;
        float rw1 = rsqrtf(v1 + 1e-5f) * pwtB1;
#pragma unroll
        for (int i = 0; i < 4; ++i) {
          oa0[i] = fmaf((pyB0[i] - m0) * rw0, plgB[i], fmaf(pwtB0, plbB[i], oa0[i]));
          oa1[i] = fmaf((pyB1[i] - m1) * rw1, plgB[i], fmaf(pwtB1, plbB[i], oa1[i]));
        }
      }
    }

    // ================= feature g =================
    {
      const float* sp = scal + (size_t)g * 640 + h0;
      float4v bcv = *(const float4v*)(sp);
      float4v bcg = *(const float4v*)(sp + 128);
      float4v fs4 = *(const float4v*)(sp + 256);
      float4v lg4 = *(const float4v*)(sp + 384);
      float4v lb4 = *(const float4v*)(sp + 512);

      float4v av0 = (float4v){0.f,0.f,0.f,0.f}, ag0 = av0, av1 = av0, ag1 = av0;
#pragma unroll
      for (int ks = 0; ks < 4; ++ks) {
        int b0 = tk * 256 + (ks * 32 + rg * 8) * 2;
        b0 ^= (tk & 7) << 4;
        short8 hf0 = *(const short8*)((const char*)a_lds[bufp] + b0);
        int b1 = (16 + tk) * 256 + (ks * 32 + rg * 8) * 2;
        b1 ^= (tk & 7) << 4;
        short8 hf1 = *(const short8*)((const char*)a_lds[bufp] + b1);
        av0 = __builtin_amdgcn_mfma_f32_16x16x32_bf16(aV[ks], hf0, av0, 0, 0, 0);
        ag0 = __builtin_amdgcn_mfma_f32_16x16x32_bf16(aG[ks], hf0, ag0, 0, 0, 0);
        av1 = __builtin_amdgcn_mfma_f32_16x16x32_bf16(aV[ks], hf1, av1, 0, 0, 0);
        ag1 = __builtin_amdgcn_mfma_f32_16x16x32_bf16(aG[ks], hf1, ag1, 0, 0, 0);
      }

      float xt0 = x_lds[g * TOKB + tk],      wt0 = w_lds[g * TOKB + tk];
      float xt1 = x_lds[g * TOKB + 16 + tk], wt1 = w_lds[g * TOKB + 16 + tk];
      float s0 = 0.f, ss0 = 0.f, s1 = 0.f, ss1 = 0.f;
#pragma unroll
      for (int i = 0; i < 4; ++i) {
        float ya = fmaf(xt0, fs4[i], (av0[i] + bcv[i]) * sigm_f(ag0[i] + bcg[i]));
        float yb = fmaf(xt1, fs4[i], (av1[i] + bcv[i]) * sigm_f(ag1[i] + bcg[i]));
        pyA0[i] = ya; pyA1[i] = yb;
        s0 += ya; ss0 = fmaf(ya, ya, ss0);
        s1 += yb; ss1 = fmaf(yb, yb, ss1);
      }
      s0  += __shfl_xor(s0, 16);  s0  += __shfl_xor(s0, 32);
      ss0 += __shfl_xor(ss0, 16); ss0 += __shfl_xor(ss0, 32);
      s1  += __shfl_xor(s1, 16);  s1  += __shfl_xor(s1, 32);
      ss1 += __shfl_xor(ss1, 16); ss1 += __shfl_xor(ss1, 32);
      if (rg == 0) {
        atomicAdd(&sred[p][0][0][tk], s0);
        atomicAdd(&sred[p][0][0][16 + tk], s1);
      } else if (rg == 1) {
        atomicAdd(&sred[p][0][1][tk], ss0);
        atomicAdd(&sred[p][0][1][16 + tk], ss1);
      }
      plgA = lg4; plbA = lb4; pwtA0 = wt0; pwtA1 = wt1;
    }

    // ---- A-frags for feature g+1 (reuse aV/aG registers) ----
    {
      const unsigned short* bb = bfrag + (((size_t)(g + 1) * 8 + w) * 8) * 512 + (size_t)l * 8;
#pragma unroll
      for (int ks = 0; ks < 4; ++ks) {
        aV[ks] = *(const short8*)(bb + (size_t)ks * 512);
        aG[ks] = *(const short8*)(bb + (size_t)(4 + ks) * 512);
      }
    }

    // ================= feature g+1 =================
    {
      const float* sp = scal + (size_t)(g + 1) * 640 + h0;
      float4v bcv = *(const float4v*)(sp);
      float4v bcg = *(const float4v*)(sp + 128);
      float4v fs4 = *(const float4v*)(sp + 256);
      float4v lg4 = *(const float4v*)(sp + 384);
      float4v lb4 = *(const float4v*)(sp + 512);

      float4v av0 = (float4v){0.f,0.f,0.f,0.f}, ag0 = av0, av1 = av0, ag1 = av0;
#pragma unroll
      for (int ks = 0; ks < 4; ++ks) {
        int b0 = tk * 256 + (ks * 32 + rg * 8) * 2;
        b0 ^= (tk & 7) << 4;
        short8 hf0 = *(const short8*)((const char*)a_lds[bufp + 1] + b0);
        int b1 = (16 + tk) * 256 + (ks * 32 + rg * 8) * 2;
        b1 ^= (tk & 7) << 4;
        short8 hf1 = *(const short8*)((const char*)a_lds[bufp + 1] + b1);
        av0 = __builtin_amdgcn_mfma_f32_16x16x32_bf16(aV[ks], hf0, av0, 0, 0, 0);
        ag0 = __builtin_amdgcn_mfma_f32_16x16x32_bf16(aG[ks], hf0, ag0, 0, 0, 0);
        av1 = __builtin_amdgcn_mfma_f32_16x16x32_bf16(aV[ks], hf1, av1, 0, 0, 0);
        ag1 = __builtin_amdgcn_mfma_f32_16x16x32_bf16(aG[ks], hf1, ag1, 0, 0, 0);
      }

      float xt0 = x_lds[(g + 1) * TOKB + tk],      wt0 = w_lds[(g + 1) * TOKB + tk];
      float xt1 = x_lds[(g + 1) * TOKB + 16 + tk], wt1 = w_lds[(g + 1) * TOKB + 16 + tk];
      float s0 = 0.f, ss0 = 0.f, s1 = 0.f, ss1 = 0.f;
#pragma unroll
      for (int i = 0; i < 4; ++i) {
        float ya = fmaf(xt0, fs4[i], (av0[i] + bcv[i]) * sigm_f(ag0[i] + bcg[i]));
        float yb = fmaf(xt1, fs4[i], (av1[i] + bcv[i]) * sigm_f(ag1[i] + bcg[i]));
        pyB0[i] = ya; pyB1[i] = yb;
        s0 += ya; ss0 = fmaf(ya, ya, ss0);
        s1 += yb; ss1 = fmaf(yb, yb, ss1);
      }
      s0  += __shfl_xor(s0, 16);  s0  += __shfl_xor(s0, 32);
      ss0 += __shfl_xor(ss0, 16); ss0 += __shfl_xor(ss0, 32);
      s1  += __shfl_xor(s1, 16);  s1  += __shfl_xor(s1, 32);
      ss1 += __shfl_xor(ss1, 16); ss1 += __shfl_xor(ss1, 32);
      if (rg == 0) {
        atomicAdd(&sred[p][1][0][tk], s0);
        atomicAdd(&sred[p][1][0][16 + tk], s1);
      } else if (rg == 1) {
        atomicAdd(&sred[p][1][1][tk], ss0);
        atomicAdd(&sred[p][1][1][16 + tk], ss1);
      }
      plgB = lg4; plbB = lb4; pwtB0 = wt0; pwtB1 = wt1;
    }

    // zero the pair-buffer used at iter k+1 (barrier-separated both ways)
    {
      const int pn = (p == 2) ? 0 : p + 1;
      if (tid < 128) ((float*)(sred[pn]))[tid] = 0.f;
      p = pn;
    }
  }

  // ---- tail: finalize pair 15 (features 30, 31) ----
  __syncthreads();
  {
    const int pp = (p == 0) ? 2 : p - 1;
    {
      float sA  = sred[pp][0][0][tk],      ssA = sred[pp][0][1][tk];
      float sB  = sred[pp][0][0][16 + tk], ssB = sred[pp][0][1][16 + tk];
      float m0 = sA * (1.f / 128.f);
      float m1 = sB * (1.f / 128.f);
      float v0 = fmaf(-m0, m0, ssA * (1.f / 128.f));
      float v1 = fmaf(-m1, m1, ssB * (1.f / 128.f));
      float rw0 = rsqrtf(v0 + 1e-5f) * pwtA0;
      float rw1 = rsqrtf(v1 + 1e-5f) * pwtA1;
#pragma unroll
      for (int i = 0; i < 4; ++i) {
        oa0[i] = fmaf((pyA0[i] - m0) * rw0, plgA[i], fmaf(pwtA0, plbA[i], oa0[i]));
        oa1[i] = fmaf((pyA1[i] - m1) * rw1, plgA[i], fmaf(pwtA1, plbA[i], oa1[i]));
      }
    }
    {
      float sA  = sred[pp][1][0][tk],      ssA = sred[pp][1][1][tk];
      float sB  = sred[pp][1][0][16 + tk], ssB = sred[pp][1][1][16 + tk];
      float m0 = sA * (1.f / 128.f);
      float m1 = sB * (1.f / 128.f);
      float v0 = fmaf(-m0, m0, ssA * (1.f / 128.f));
      float v1 = fmaf(-m1, m1, ssB * (1.f / 128.f));
      float rw0 = rsqrtf(v0 + 1e-5f) * pwtB0;
      float rw1 = rsqrtf(v1 + 1e-5f) * pwtB1;
#pragma unroll
      for (int i = 0; i < 4; ++i) {
        oa0[i] = fmaf((pyB0[i] - m0) * rw0, plgB[i], fmaf(pwtB0, plbB[i], oa0[i]));
        oa1[i] = fmaf((pyB1[i] - m1) * rw1, plgB[i], fmaf(pwtB1, plbB[i], oa1[i]));
      }
    }
  }

  // ---- store: per lane 2 x 16B contiguous ----
  *(float4v*)(out + (size_t)(t0 + tk) * HDIM + h0)      = oa0;
  *(float4v*)(out + (size_t)(t0 + 16 + tk) * HDIM + h0) = oa1;
}

extern "C" void kernel_launch(void* const* d_in, const int* in_sizes, int n_in,
                              void* d_out, int out_size, void* d_ws, size_t ws_size,
                              hipStream_t stream) {
  const float* x      = (const float*)d_in[0];
  const float* fw1    = (const float*)d_in[1];
  const float* fb1    = (const float*)d_in[2];
  const float* fw2    = (const float*)d_in[3];
  const float* fb2    = (const float*)d_in[4];
  const float* fglu_w = (const float*)d_in[5];
  const float* fglu_b = (const float*)d_in[6];
  const float* fskip  = (const float*)d_in[7];
  const float* fln_g  = (const float*)d_in[8];
  const float* fln_b  = (const float*)d_in[9];
  const float* ww1    = (const float*)d_in[10];
  const float* wb1    = (const float*)d_in[11];
  const float* ww2    = (const float*)d_in[12];
  const float* wb2    = (const float*)d_in[13];
  const float* wglu_w = (const float*)d_in[14];
  const float* wglu_b = (const float*)d_in[15];
  const float* wln_g  = (const float*)d_in[16];
  const float* wln_b  = (const float*)d_in[17];

  float* outp = (float*)d_out;
  float* wout = outp + (size_t)NTOK * HDIM;

  unsigned short* bfrag = (unsigned short*)d_ws;                  // 2 MiB bf16
  float* scal = (float*)((char*)d_ws + (size_t)2 * 1024 * 1024);  // 80 KiB f32

  k_pw<<<dim3(256 + NTOK / 8), dim3(256), 0, stream>>>(
      x, fw2, fb2, fglu_w, fglu_b, fskip, fln_g, fln_b,
      ww1, wb1, ww2, wb2, wglu_w, wglu_b, wln_g, wln_b,
      bfrag, scal, wout);
  k_main<<<dim3(NTOK / TOKB), dim3(512), 0, stream>>>(
      x, fw1, fb1, bfrag, scal, wout, outp);
}